// Round 2
// baseline (1455.179 us; speedup 1.0000x reference)
//
#include <hip/hip_runtime.h>
#include <cstdint>
#include <cstddef>

#define Dd 768
#define Ff 16384
#define Bb 4096
#define Kk 64
#define NCAND 128         // candidate cap per row (expected ~84)
#define BINS 512          // histogram bins over [0,4), width 1/128
#define MARGIN 0.04f      // 2*(screen err + bf16 storage round) + bin width

typedef __bf16 bf16x8 __attribute__((ext_vector_type(8)));
typedef float  f32x4  __attribute__((ext_vector_type(4)));
typedef unsigned short u16x8 __attribute__((ext_vector_type(8)));

__device__ __forceinline__ unsigned short f2bf(float f) {
    union { float f; unsigned u; } a; a.f = f;
    unsigned r = a.u + 0x7fffu + ((a.u >> 16) & 1u);   // RNE
    return (unsigned short)(r >> 16);
}
__device__ __forceinline__ float bf2f(unsigned short h) {
    union { float f; unsigned u; } a; a.u = ((unsigned)h) << 16;
    return a.f;
}
__device__ __forceinline__ float f_lo(unsigned u) {    // low bf16 of a u32
    union { float f; unsigned u; } a; a.u = u << 16; return a.f;
}
__device__ __forceinline__ float f_hi(unsigned u) {    // high bf16 of a u32
    union { float f; unsigned u; } a; a.u = u & 0xffff0000u; return a.f;
}

#define GLDS16(g, l) __builtin_amdgcn_global_load_lds( \
    (const __attribute__((address_space(1))) void*)(g), \
    (__attribute__((address_space(3))) void*)(l), 16, 0, 0)

// ---------------- pack x - b_dec into bf16 ----------------
__global__ __launch_bounds__(256) void conv_x(
    const float* __restrict__ x, const float* __restrict__ bdec,
    unsigned short* __restrict__ Xb)
{
    const int i = blockIdx.x * 256 + threadIdx.x;        // over Bb*Dd
    const int col = i % Dd;
    Xb[i] = f2bf(x[i] - bdec[col]);
}

// ---------------- pack W_enc into bf16 ----------------
__global__ __launch_bounds__(256) void conv_w(
    const float* __restrict__ Wenc, unsigned short* __restrict__ Wb)
{
    const int i = blockIdx.x * 256 + threadIdx.x;        // over Ff*Dd
    Wb[i] = f2bf(Wenc[i]);
}

// ---------------- bf16 screen GEMM: 256x256 tile, 2 blocks/CU ---------------
// 512 threads = 8 waves (2M x 4N); per-wave output 128x64 = acc[8][4] f32x4.
// BK=32, 2 LDS buffers: A/B each [2][256 rows][32 k] bf16 = 64 KB total ->
// 2 blocks/CU (cross-block MFMA/LDS/epilogue overlap replaces the missing
// cross-wave stagger of the 1-block lockstep schedule).
// Rotation swizzle: phys slot16 = (q + row/2)&3 (conflict-free ds_read_b128);
// staged via global_load_lds(16B) with inverse rotation on per-lane source.
// Per tile t (buf=t&1): PH(H=0: 8 reads,16 MFMA) PH(H=1: 4 reads,16 MFMA),
// then STAGE(t+2 -> same buf) + vmcnt(4) + barrier. Stage is issued only
// after the barrier following all lgkm-completed reads of tile t (overwrite-
// safe); VM4+barrier guarantees tile t+1 landed cross-wave before its reads.
// Last two tiles peeled (no staging, vmcnt(0)) -> nothing in flight at exit.
// MFMA operands SWAPPED: mfma(B,A) -> per lane C holds m=lane&15 fixed,
// n=(lane>>4)*4+j consecutive -> epilogue packs 4 bf16 = one 8B store
// (32 stores/thread, full-line write combining). Same products, same K
// order -> bit-identical pre[].
// XCD swizzle: each XCD owns 8 N-panels (3.1 MB B, L2-resident) sweeping M.
__global__ __launch_bounds__(512, 4) void sae_gemm(
    const unsigned short* __restrict__ Xb,   // [Bb][Dd]
    const unsigned short* __restrict__ Wb,   // [Ff][Dd]
    const float* __restrict__ benc,
    unsigned short* __restrict__ pre)        // [Bb][Ff] bf16
{
    __shared__ __align__(16) unsigned short As[16384];   // 32 KB (2 bufs)
    __shared__ __align__(16) unsigned short Bs[16384];   // 32 KB

    const int tid  = threadIdx.x;
    const int lane = tid & 63;
    const int w    = tid >> 6;
    const int wm   = w >> 2, wn = w & 3;     // 2x4 wave grid

    // XCD-aware N-chunked swizzle (1024 blocks, bijective):
    // xcd = bid&7 owns n-tiles [xcd*8, xcd*8+8); m sweeps slowly.
    const int bid = blockIdx.x;
    const int xcd = bid & 7;
    const int c   = bid >> 3;                // 0..127
    const int n0  = (xcd * 8 + (c & 7)) * 256;
    const int m0  = (c >> 3) * 256;

    // ---- staging source bases (inverse-rotation pre-applied per thread) ----
    // phys chunk P (512/call): row = P>>2 ; logical q = (P - P>>3) & 3
    const int r0 = tid >> 2,           r1 = (512 + tid) >> 2;
    const int q0 = (tid - (tid >> 3)) & 3;
    const int q1 = ((512 + tid) - ((512 + tid) >> 3)) & 3;
    const unsigned short* aS0 = Xb + (size_t)(m0 + r0) * Dd + q0 * 8;
    const unsigned short* aS1 = Xb + (size_t)(m0 + r1) * Dd + q1 * 8;
    const unsigned short* bS0 = Wb + (size_t)(n0 + r0) * Dd + q0 * 8;
    const unsigned short* bS1 = Wb + (size_t)(n0 + r1) * Dd + q1 * 8;
    unsigned short* lA = As + w * 512;       // wave-uniform base (+lane*16B HW)
    unsigned short* lB = Bs + w * 512;

    // ---- ds_read bases (byte LDS offsets, rotation-swizzled) ----
    const int rl  = lane & 15;
    const int rot = ((lane >> 4) + (rl >> 1)) & 3;
    const unsigned asO = (unsigned)(unsigned long long)
        (__attribute__((address_space(3))) unsigned short*)&As[0];
    const unsigned bsO = (unsigned)(unsigned long long)
        (__attribute__((address_space(3))) unsigned short*)&Bs[0];
    const unsigned aRd = asO + (unsigned)((wm * 128 + rl) * 64 + rot * 16);
    const unsigned bRd = bsO + (unsigned)((wn * 64 + rl) * 64 + rot * 16);

    f32x4 acc[8][4];
    #pragma unroll
    for (int i = 0; i < 8; ++i)
        #pragma unroll
        for (int j = 0; j < 4; ++j) acc[i][j] = 0;

#define DSR(D, A) asm volatile("ds_read_b128 %0, %1" : "=v"(D) : "v"(A))
#define STG(TILE, BUF) {                                                      \
    GLDS16(aS0 + (TILE) * 32, lA + (BUF) * 8192);                             \
    GLDS16(aS1 + (TILE) * 32, lA + (BUF) * 8192 + 4096);                      \
    GLDS16(bS0 + (TILE) * 32, lB + (BUF) * 8192);                             \
    GLDS16(bS1 + (TILE) * 32, lB + (BUF) * 8192 + 4096); }
#define VM4 asm volatile("s_waitcnt vmcnt(4)" ::: "memory")
#define VM0 asm volatile("s_waitcnt vmcnt(0)" ::: "memory")

// SWAPPED operands: D = bfr * af -> lane holds m=lane&15, n=(lane>>4)*4+j
#define MF1(H, MI, NI) acc[(H)*4+(MI)][(NI)] =                                \
    __builtin_amdgcn_mfma_f32_16x16x32_bf16(                                  \
        __builtin_bit_cast(bf16x8, bfr[(NI)]),                                \
        __builtin_bit_cast(bf16x8, af[(MI)]), acc[(H)*4+(MI)][(NI)], 0, 0, 0)
#define MFQ(H)                                                                \
    MF1(H,0,0); MF1(H,0,1); MF1(H,0,2); MF1(H,0,3);                           \
    MF1(H,1,0); MF1(H,1,1); MF1(H,1,2); MF1(H,1,3);                           \
    MF1(H,2,0); MF1(H,2,1); MF1(H,2,2); MF1(H,2,3);                           \
    MF1(H,3,0); MF1(H,3,1); MF1(H,3,2); MF1(H,3,3)

#define PH(BUF, H) {                                                          \
    f32x4 af[4];                                                              \
    const unsigned ab = aRd + (BUF)*16384 + (H)*4096;                         \
    DSR(af[0], ab);        DSR(af[1], ab + 1024);                             \
    DSR(af[2], ab + 2048); DSR(af[3], ab + 3072);                             \
    if ((H) == 0) {                                                           \
        const unsigned bb = bRd + (BUF)*16384;                                \
        DSR(bfr[0], bb);        DSR(bfr[1], bb + 1024);                       \
        DSR(bfr[2], bb + 2048); DSR(bfr[3], bb + 3072);                       \
    }                                                                         \
    __builtin_amdgcn_s_barrier();                                             \
    asm volatile("s_waitcnt lgkmcnt(0)" ::: "memory");                        \
    __builtin_amdgcn_sched_barrier(0);                                        \
    __builtin_amdgcn_s_setprio(1);                                            \
    MFQ(H);                                                                   \
    __builtin_amdgcn_s_setprio(0);                                            \
    __builtin_amdgcn_s_barrier(); }

    // prologue: stage tiles 0,1; wait tile 0; barrier makes it cross-wave
    STG(0, 0);
    STG(1, 1);
    VM4;
    __builtin_amdgcn_s_barrier();

    f32x4 bfr[4];
    for (int t = 0; t < 22; t += 2) {        // tiles t (buf0), t+1 (buf1)
        PH(0, 0); PH(0, 1);
        STG(t + 2, 0); VM4; __builtin_amdgcn_s_barrier();
        PH(1, 0); PH(1, 1);
        STG(t + 3, 1); VM4; __builtin_amdgcn_s_barrier();
    }
    // tiles 22 (buf0), 23 (buf1) — no staging
    PH(0, 0); PH(0, 1);
    VM0; __builtin_amdgcn_s_barrier();
    PH(1, 0); PH(1, 1);

    // epilogue (swapped layout): row m = ...+mi*16+(lane&15) fixed per lane;
    // cols n = ...+ni*16+(lane>>4)*4 + j consecutive -> pack 4 bf16 = 8B store
    const int rl2  = lane & 15;
    const int cg   = (lane >> 4) * 4;
    const int colb = n0 + wn * 64;
    float4 bia[4];
    #pragma unroll
    for (int ni = 0; ni < 4; ++ni)
        bia[ni] = *(const float4*)&benc[colb + ni * 16 + cg];
    #pragma unroll
    for (int mi = 0; mi < 8; ++mi) {
        const int row = m0 + wm * 128 + mi * 16 + rl2;
        unsigned short* prow = pre + (size_t)row * Ff + colb;
        #pragma unroll
        for (int ni = 0; ni < 4; ++ni) {
            const f32x4 a = acc[mi][ni];
            uint2 pk;
            pk.x = (unsigned)f2bf(a[0] + bia[ni].x)
                 | ((unsigned)f2bf(a[1] + bia[ni].y) << 16);
            pk.y = (unsigned)f2bf(a[2] + bia[ni].z)
                 | ((unsigned)f2bf(a[3] + bia[ni].w) << 16);
            *(uint2*)(prow + ni * 16 + cg) = pk;
        }
    }

#undef DSR
#undef STG
#undef VM4
#undef VM0
#undef MF1
#undef MFQ
#undef PH
}

// ---------------- histogram select: per-row tau + compaction ----------------
// 2 rows/block, 128 threads/row, full F per row (bf16 pre).
__global__ __launch_bounds__(256) void sae_select(
    const unsigned short* __restrict__ pre,  // [Bb][Ff] bf16
    int* __restrict__ ci, int* __restrict__ ccount)
{
    __shared__ unsigned hist[2][BINS];
    __shared__ float tauS[2];
    __shared__ int lcnt[2];

    const int tid = threadIdx.x;
    const int r   = tid >> 7;                // 0..1
    const int l   = tid & 127;
    const int rg  = blockIdx.x * 2 + r;      // global row

    for (int i = tid; i < 2 * BINS; i += 256) ((unsigned*)hist)[i] = 0;
    if (tid < 2) lcnt[tid] = 0;
    __syncthreads();

    const u16x8* rp = (const u16x8*)(pre + (size_t)rg * Ff);  // 2048 vecs/row
    for (int j = 0; j < 16; ++j) {
        const u16x8 v8 = rp[j * 128 + l];
        #pragma unroll
        for (int c = 0; c < 8; ++c) {
            const float v = bf2f(v8[c]);
            if (v >= 0.0f) {
                const int b = min((int)(v * 128.0f), BINS - 1);
                atomicAdd(&hist[r][b], 1u);
            }
        }
    }
    __syncthreads();

    if (l == 0) {                            // threads 0 and 128
        unsigned acc = 0; float tv = -1.0e30f;
        for (int j = BINS - 1; j >= 0; --j) {
            acc += hist[r][j];
            if (acc >= (unsigned)Kk) { tv = (float)j * 0.0078125f; break; }
        }
        tauS[r] = tv;
    }
    __syncthreads();

    const float thr = tauS[r] - MARGIN;
    for (int j = 0; j < 16; ++j) {
        const u16x8 v8 = rp[j * 128 + l];
        #pragma unroll
        for (int c = 0; c < 8; ++c) {
            const float v = bf2f(v8[c]);
            if (v >= thr) {
                const int p = atomicAdd(&lcnt[r], 1);
                if (p < NCAND) ci[(size_t)rg * NCAND + p] = j * 1024 + l * 8 + c;
            }
        }
    }
    __syncthreads();
    if (l == 0) ccount[rg] = min(lcnt[r], NCAND);
}

// ---------------- exact fp64 rescore + final top-64 (R4-proven form) --------
__global__ __launch_bounds__(256) void sae_rescore(
    const float* __restrict__ x, const float* __restrict__ Wenc,
    const float* __restrict__ benc, const float* __restrict__ bdec,
    const int* __restrict__ ci, const int* __restrict__ ccount,
    float* __restrict__ ovals, int* __restrict__ oidx)
{
    __shared__ float  xr[Dd];
    __shared__ int    cis[NCAND];
    __shared__ double es[NCAND];
    __shared__ int    cnt;

    const int r = blockIdx.x, tid = threadIdx.x;
    const int lane = tid & 63, w = tid >> 6;

    xr[tid]       = x[(size_t)r * Dd + tid]       - bdec[tid];
    xr[tid + 256] = x[(size_t)r * Dd + tid + 256] - bdec[tid + 256];
    xr[tid + 512] = x[(size_t)r * Dd + tid + 512] - bdec[tid + 512];
    if (tid == 0) cnt = ccount[r];
    if (tid < NCAND) cis[tid] = ci[(size_t)r * NCAND + tid];
    if (tid < Kk) { ovals[(size_t)r * Kk + tid] = 0.0f; oidx[(size_t)r * Kk + tid] = 0; }
    __syncthreads();

    for (int c = w; c < NCAND; c += 4) {
        double e = -1.0e300;
        if (c < cnt) {
            const int f = cis[c];
            const float* wrow = Wenc + (size_t)f * Dd;
            double a = 0.0;
            #pragma unroll
            for (int j = 0; j < Dd / 64; ++j)
                a = fma((double)wrow[j * 64 + lane], (double)xr[j * 64 + lane], a);
            #pragma unroll
            for (int off = 32; off > 0; off >>= 1)
                a += __shfl_xor(a, off);
            e = a + (double)benc[f];
        }
        if (lane == 0) es[c] = e;
    }
    __syncthreads();

    if (tid < NCAND) {
        const double e = es[tid];
        int rk = 0;
        for (int j = 0; j < NCAND; ++j) {
            const double ej = es[j];
            rk += (ej > e) || (ej == e && j < tid);
        }
        if (tid < cnt && rk < Kk) {
            ovals[(size_t)r * Kk + rk] = (float)e;
            oidx [(size_t)r * Kk + rk] = cis[tid];
        }
    }
}

// ---------------- W_dec transpose: [D][F] fp32 -> [F][D] bf16 ----------------
__global__ __launch_bounds__(256) void sae_transpose(
    const float* __restrict__ Wd, unsigned short* __restrict__ WdT)
{
    __shared__ float tile[32][33];
    const int f0 = blockIdx.x * 32;
    const int d0 = blockIdx.y * 32;
    const int tx = threadIdx.x, ty = threadIdx.y;
    #pragma unroll
    for (int k = 0; k < 4; ++k)
        tile[ty + 8 * k][tx] = Wd[(size_t)(d0 + ty + 8 * k) * Ff + f0 + tx];
    __syncthreads();
    #pragma unroll
    for (int k = 0; k < 4; ++k)
        WdT[(size_t)(f0 + ty + 8 * k) * Dd + d0 + tx] = f2bf(tile[tx][ty + 8 * k]);
}

// ---------------- sparse decode (bf16 WdT, LLC-resident) ----------------
// 192 threads: thread t covers d in [4t, 4t+4), reads uint2 (4 bf16) per k.
__global__ __launch_bounds__(192) void sae_decode(
    const unsigned short* __restrict__ WdT, const float* __restrict__ vals,
    const int* __restrict__ idx, const float* __restrict__ bdec,
    float* __restrict__ out)
{
    __shared__ float sv[Kk];
    __shared__ int   si[Kk];
    const int b = blockIdx.x, tid = threadIdx.x;
    if (tid < Kk) { sv[tid] = vals[(size_t)b * Kk + tid]; si[tid] = idx[(size_t)b * Kk + tid]; }
    __syncthreads();
    const int d0 = tid * 4;
    float a0 = bdec[d0], a1 = bdec[d0 + 1], a2 = bdec[d0 + 2], a3 = bdec[d0 + 3];
    for (int k = 0; k < Kk; ++k) {
        const float v = sv[k];
        const uint2 p = *(const uint2*)(WdT + (size_t)si[k] * Dd + d0);
        a0 = fmaf(v, f_lo(p.x), a0);
        a1 = fmaf(v, f_hi(p.x), a1);
        a2 = fmaf(v, f_lo(p.y), a2);
        a3 = fmaf(v, f_hi(p.y), a3);
    }
    float4 o4 = make_float4(a0, a1, a2, a3);
    *(float4*)(out + (size_t)b * Dd + d0) = o4;
}

extern "C" void kernel_launch(void* const* d_in, const int* in_sizes, int n_in,
                              void* d_out, int out_size, void* d_ws, size_t ws_size,
                              hipStream_t stream) {
    const float* x    = (const float*)d_in[0];
    const float* Wenc = (const float*)d_in[1];
    const float* benc = (const float*)d_in[2];
    const float* Wdec = (const float*)d_in[3];
    const float* bdec = (const float*)d_in[4];
    float* out = (float*)d_out;

    char* ws = (char*)d_ws;
    size_t o = 0;
    unsigned short* pre  = (unsigned short*)(ws + o); o += (size_t)Bb * Ff * 2;     // 134.2 MB
    unsigned short* Xb   = (unsigned short*)(ws + o); o += (size_t)Bb * Dd * 2;     //   6.3 MB
    unsigned short* Wb   = (unsigned short*)(ws + o); o += (size_t)Ff * Dd * 2;     //  25.2 MB
    unsigned short* WdT  = (unsigned short*)(ws + o); o += (size_t)Ff * Dd * 2;     //  25.2 MB
    int*            cib  = (int*)(ws + o);            o += (size_t)Bb * NCAND * 4;  //   2.1 MB
    int*            ccnt = (int*)(ws + o);            o += (size_t)Bb * 4;          //  16 KB
    float*          vals = (float*)(ws + o);          o += (size_t)Bb * Kk * 4;     //   1.0 MB
    int*            idxb = (int*)(ws + o);                                          //   1.0 MB

    conv_x<<<(Bb * Dd) / 256, 256, 0, stream>>>(x, bdec, Xb);
    conv_w<<<(Ff * Dd) / 256, 256, 0, stream>>>(Wenc, Wb);
    sae_gemm<<<(Bb / 256) * (Ff / 256), 512, 0, stream>>>(Xb, Wb, benc, pre);
    sae_select<<<Bb / 2, 256, 0, stream>>>(pre, cib, ccnt);
    sae_rescore<<<Bb, 256, 0, stream>>>(x, Wenc, benc, bdec, cib, ccnt, vals, idxb);
    sae_transpose<<<dim3(Ff / 32, Dd / 32), dim3(32, 8), 0, stream>>>(Wdec, WdT);
    sae_decode<<<Bb, 192, 0, stream>>>(WdT, vals, idxb, bdec, out);
}

// Round 3
// 543.872 us; speedup vs baseline: 2.6756x; 2.6756x over previous
//
#include <hip/hip_runtime.h>
#include <cstdint>
#include <cstddef>

#define Dd 768
#define Ff 16384
#define Bb 4096
#define Kk 64
#define NCAND 128         // candidate cap per row (expected ~84)
#define BINS 512          // histogram bins over [0,4), width 1/128
#define MARGIN 0.04f      // 2*(screen err + bf16 storage round) + bin width

typedef __bf16 bf16x8 __attribute__((ext_vector_type(8)));
typedef float  f32x4  __attribute__((ext_vector_type(4)));
typedef unsigned short u16x8 __attribute__((ext_vector_type(8)));

__device__ __forceinline__ unsigned short f2bf(float f) {
    union { float f; unsigned u; } a; a.f = f;
    unsigned r = a.u + 0x7fffu + ((a.u >> 16) & 1u);   // RNE
    return (unsigned short)(r >> 16);
}
__device__ __forceinline__ float bf2f(unsigned short h) {
    union { float f; unsigned u; } a; a.u = ((unsigned)h) << 16;
    return a.f;
}
__device__ __forceinline__ float f_lo(unsigned u) {    // low bf16 of a u32
    union { float f; unsigned u; } a; a.u = u << 16; return a.f;
}
__device__ __forceinline__ float f_hi(unsigned u) {    // high bf16 of a u32
    union { float f; unsigned u; } a; a.u = u & 0xffff0000u; return a.f;
}

#define GLDS16(g, l) __builtin_amdgcn_global_load_lds( \
    (const __attribute__((address_space(1))) void*)(g), \
    (__attribute__((address_space(3))) void*)(l), 16, 0, 0)

// ---------------- pack x - b_dec into bf16 ----------------
__global__ __launch_bounds__(256) void conv_x(
    const float* __restrict__ x, const float* __restrict__ bdec,
    unsigned short* __restrict__ Xb)
{
    const int i = blockIdx.x * 256 + threadIdx.x;        // over Bb*Dd
    const int col = i % Dd;
    Xb[i] = f2bf(x[i] - bdec[col]);
}

// ---------------- pack W_enc into bf16 ----------------
__global__ __launch_bounds__(256) void conv_w(
    const float* __restrict__ Wenc, unsigned short* __restrict__ Wb)
{
    const int i = blockIdx.x * 256 + threadIdx.x;        // over Ff*Dd
    Wb[i] = f2bf(Wenc[i]);
}

// ---------------- bf16 screen GEMM: 256x256 tile, 4-deep pipeline -----------
// 512 threads = 8 waves (2M x 4N); per-wave output 128x64 = acc[8][4] f32x4.
// __launch_bounds__(512,2): 256-VGPR cap -> NO accumulator spill (R2's
// (512,4) forced a 128-VGPR cap -> acc spilled to scratch -> 3 GB writes).
// BK=32, FOUR LDS buffers: A/B each [4][256 rows][32 k] bf16 = 128 KB total.
// Per slot t (buf=t&3): PH(H0: 8 reads,16 MFMA) PH(H1: 4 reads,16 MFMA),
// STG(t+4 -> buf, freed by H1's closing barrier), vmcnt(12) (12 loads =
// tiles t+1..t+3 stay in flight; oldest 4 = tile t+1 land here), barrier.
// Continuous 12 KB vmem in flight per wave-group -> no dead memory windows.
// Tail (tiles 20..23) peels with VM8/VM4/VM0 -> nothing in flight at exit.
// Rotation swizzle: phys slot16 = (q + row/2)&3, conflict-free ds_read_b128;
// staged via global_load_lds(16B) with inverse rotation on per-lane source.
// MFMA operands SWAPPED: mfma(B,A) -> lane holds m=lane&15, n consecutive ->
// epilogue packs 4 bf16 = one 8B store. Same products, same K order.
// XCD swizzle: each XCD owns 8 N-panels (3.1 MB B-slice L2-resident), A
// streamed -> compulsory-ish fetch (~73 MB chip-wide).
__global__ __launch_bounds__(512, 2) void sae_gemm(
    const unsigned short* __restrict__ Xb,   // [Bb][Dd]
    const unsigned short* __restrict__ Wb,   // [Ff][Dd]
    const float* __restrict__ benc,
    unsigned short* __restrict__ pre)        // [Bb][Ff] bf16
{
    __shared__ __align__(16) unsigned short As[32768];   // 64 KB (4 bufs)
    __shared__ __align__(16) unsigned short Bs[32768];   // 64 KB

    const int tid  = threadIdx.x;
    const int lane = tid & 63;
    const int w    = tid >> 6;
    const int wm   = w >> 2, wn = w & 3;     // 2x4 wave grid

    // XCD-aware N-chunked swizzle (1024 blocks, bijective):
    // xcd = bid&7 owns n-tiles [xcd*8, xcd*8+8); m sweeps slowly.
    const int bid = blockIdx.x;
    const int xcd = bid & 7;
    const int c   = bid >> 3;                // 0..127
    const int n0  = (xcd * 8 + (c & 7)) * 256;
    const int m0  = (c >> 3) * 256;

    // ---- staging source bases (inverse-rotation pre-applied per thread) ----
    // phys chunk P (512/call): row = P>>2 ; logical q = (P - P>>3) & 3
    const int r0 = tid >> 2,           r1 = (512 + tid) >> 2;
    const int q0 = (tid - (tid >> 3)) & 3;
    const int q1 = ((512 + tid) - ((512 + tid) >> 3)) & 3;
    const unsigned short* aS0 = Xb + (size_t)(m0 + r0) * Dd + q0 * 8;
    const unsigned short* aS1 = Xb + (size_t)(m0 + r1) * Dd + q1 * 8;
    const unsigned short* bS0 = Wb + (size_t)(n0 + r0) * Dd + q0 * 8;
    const unsigned short* bS1 = Wb + (size_t)(n0 + r1) * Dd + q1 * 8;
    unsigned short* lA = As + w * 512;       // wave-uniform base (+lane*16B HW)
    unsigned short* lB = Bs + w * 512;

    // ---- ds_read bases (byte LDS offsets, rotation-swizzled) ----
    const int rl  = lane & 15;
    const int rot = ((lane >> 4) + (rl >> 1)) & 3;
    const unsigned asO = (unsigned)(unsigned long long)
        (__attribute__((address_space(3))) unsigned short*)&As[0];
    const unsigned bsO = (unsigned)(unsigned long long)
        (__attribute__((address_space(3))) unsigned short*)&Bs[0];
    const unsigned aRd = asO + (unsigned)((wm * 128 + rl) * 64 + rot * 16);
    const unsigned bRd = bsO + (unsigned)((wn * 64 + rl) * 64 + rot * 16);

    f32x4 acc[8][4];
    #pragma unroll
    for (int i = 0; i < 8; ++i)
        #pragma unroll
        for (int j = 0; j < 4; ++j) acc[i][j] = 0;

#define DSR(D, A) asm volatile("ds_read_b128 %0, %1" : "=v"(D) : "v"(A))
#define STG(TILE, BUF) {                                                      \
    GLDS16(aS0 + (TILE) * 32, lA + (BUF) * 8192);                             \
    GLDS16(aS1 + (TILE) * 32, lA + (BUF) * 8192 + 4096);                      \
    GLDS16(bS0 + (TILE) * 32, lB + (BUF) * 8192);                             \
    GLDS16(bS1 + (TILE) * 32, lB + (BUF) * 8192 + 4096); }
#define VM12 asm volatile("s_waitcnt vmcnt(12)" ::: "memory")
#define VM8  asm volatile("s_waitcnt vmcnt(8)"  ::: "memory")
#define VM4  asm volatile("s_waitcnt vmcnt(4)"  ::: "memory")
#define VM0  asm volatile("s_waitcnt vmcnt(0)"  ::: "memory")
#define BAR  __builtin_amdgcn_s_barrier()

// SWAPPED operands: D = bfr * af -> lane holds m=lane&15, n=(lane>>4)*4+j
#define MF1(H, MI, NI) acc[(H)*4+(MI)][(NI)] =                                \
    __builtin_amdgcn_mfma_f32_16x16x32_bf16(                                  \
        __builtin_bit_cast(bf16x8, bfr[(NI)]),                                \
        __builtin_bit_cast(bf16x8, af[(MI)]), acc[(H)*4+(MI)][(NI)], 0, 0, 0)
#define MFQ(H)                                                                \
    MF1(H,0,0); MF1(H,0,1); MF1(H,0,2); MF1(H,0,3);                           \
    MF1(H,1,0); MF1(H,1,1); MF1(H,1,2); MF1(H,1,3);                           \
    MF1(H,2,0); MF1(H,2,1); MF1(H,2,2); MF1(H,2,3);                           \
    MF1(H,3,0); MF1(H,3,1); MF1(H,3,2); MF1(H,3,3)

#define PH(BUF, H) {                                                          \
    f32x4 af[4];                                                              \
    const unsigned ab = aRd + (BUF)*16384 + (H)*4096;                         \
    DSR(af[0], ab);        DSR(af[1], ab + 1024);                             \
    DSR(af[2], ab + 2048); DSR(af[3], ab + 3072);                             \
    if ((H) == 0) {                                                           \
        const unsigned bb = bRd + (BUF)*16384;                                \
        DSR(bfr[0], bb);        DSR(bfr[1], bb + 1024);                       \
        DSR(bfr[2], bb + 2048); DSR(bfr[3], bb + 3072);                       \
    }                                                                         \
    BAR;                                                                      \
    asm volatile("s_waitcnt lgkmcnt(0)" ::: "memory");                        \
    __builtin_amdgcn_sched_barrier(0);                                        \
    __builtin_amdgcn_s_setprio(1);                                            \
    MFQ(H);                                                                   \
    __builtin_amdgcn_s_setprio(0);                                            \
    BAR; }

    // prologue: stage tiles 0..3 into bufs 0..3; wait tile 0; barrier
    STG(0, 0); STG(1, 1); STG(2, 2); STG(3, 3);
    VM12; BAR;

    f32x4 bfr[4];
    for (int i = 0; i < 5; ++i) {            // tiles 4i..4i+3, stage 4i+4..+7
        const int tb = 4 * i + 4;
        PH(0, 0); PH(0, 1); STG(tb + 0, 0); VM12; BAR;
        PH(1, 0); PH(1, 1); STG(tb + 1, 1); VM12; BAR;
        PH(2, 0); PH(2, 1); STG(tb + 2, 2); VM12; BAR;
        PH(3, 0); PH(3, 1); STG(tb + 3, 3); VM12; BAR;
    }
    // tail: tiles 20..23 — drain, no staging
    PH(0, 0); PH(0, 1); VM8; BAR;
    PH(1, 0); PH(1, 1); VM4; BAR;
    PH(2, 0); PH(2, 1); VM0; BAR;
    PH(3, 0); PH(3, 1);

    // epilogue (swapped layout): row m = ...+mi*16+(lane&15) fixed per lane;
    // cols n = ...+ni*16+(lane>>4)*4 + j consecutive -> pack 4 bf16 = 8B store
    const int rl2  = lane & 15;
    const int cg   = (lane >> 4) * 4;
    const int colb = n0 + wn * 64;
    float4 bia[4];
    #pragma unroll
    for (int ni = 0; ni < 4; ++ni)
        bia[ni] = *(const float4*)&benc[colb + ni * 16 + cg];
    #pragma unroll
    for (int mi = 0; mi < 8; ++mi) {
        const int row = m0 + wm * 128 + mi * 16 + rl2;
        unsigned short* prow = pre + (size_t)row * Ff + colb;
        #pragma unroll
        for (int ni = 0; ni < 4; ++ni) {
            const f32x4 a = acc[mi][ni];
            uint2 pk;
            pk.x = (unsigned)f2bf(a[0] + bia[ni].x)
                 | ((unsigned)f2bf(a[1] + bia[ni].y) << 16);
            pk.y = (unsigned)f2bf(a[2] + bia[ni].z)
                 | ((unsigned)f2bf(a[3] + bia[ni].w) << 16);
            *(uint2*)(prow + ni * 16 + cg) = pk;
        }
    }

#undef DSR
#undef STG
#undef VM12
#undef VM8
#undef VM4
#undef VM0
#undef BAR
#undef MF1
#undef MFQ
#undef PH
}

// ---------------- histogram select: per-row tau + compaction ----------------
// 2 rows/block, 128 threads/row, full F per row (bf16 pre).
__global__ __launch_bounds__(256) void sae_select(
    const unsigned short* __restrict__ pre,  // [Bb][Ff] bf16
    int* __restrict__ ci, int* __restrict__ ccount)
{
    __shared__ unsigned hist[2][BINS];
    __shared__ float tauS[2];
    __shared__ int lcnt[2];

    const int tid = threadIdx.x;
    const int r   = tid >> 7;                // 0..1
    const int l   = tid & 127;
    const int rg  = blockIdx.x * 2 + r;      // global row

    for (int i = tid; i < 2 * BINS; i += 256) ((unsigned*)hist)[i] = 0;
    if (tid < 2) lcnt[tid] = 0;
    __syncthreads();

    const u16x8* rp = (const u16x8*)(pre + (size_t)rg * Ff);  // 2048 vecs/row
    for (int j = 0; j < 16; ++j) {
        const u16x8 v8 = rp[j * 128 + l];
        #pragma unroll
        for (int c = 0; c < 8; ++c) {
            const float v = bf2f(v8[c]);
            if (v >= 0.0f) {
                const int b = min((int)(v * 128.0f), BINS - 1);
                atomicAdd(&hist[r][b], 1u);
            }
        }
    }
    __syncthreads();

    if (l == 0) {                            // threads 0 and 128
        unsigned acc = 0; float tv = -1.0e30f;
        for (int j = BINS - 1; j >= 0; --j) {
            acc += hist[r][j];
            if (acc >= (unsigned)Kk) { tv = (float)j * 0.0078125f; break; }
        }
        tauS[r] = tv;
    }
    __syncthreads();

    const float thr = tauS[r] - MARGIN;
    for (int j = 0; j < 16; ++j) {
        const u16x8 v8 = rp[j * 128 + l];
        #pragma unroll
        for (int c = 0; c < 8; ++c) {
            const float v = bf2f(v8[c]);
            if (v >= thr) {
                const int p = atomicAdd(&lcnt[r], 1);
                if (p < NCAND) ci[(size_t)rg * NCAND + p] = j * 1024 + l * 8 + c;
            }
        }
    }
    __syncthreads();
    if (l == 0) ccount[rg] = min(lcnt[r], NCAND);
}

// ---------------- exact fp64 rescore + final top-64 (R4-proven form) --------
__global__ __launch_bounds__(256) void sae_rescore(
    const float* __restrict__ x, const float* __restrict__ Wenc,
    const float* __restrict__ benc, const float* __restrict__ bdec,
    const int* __restrict__ ci, const int* __restrict__ ccount,
    float* __restrict__ ovals, int* __restrict__ oidx)
{
    __shared__ float  xr[Dd];
    __shared__ int    cis[NCAND];
    __shared__ double es[NCAND];
    __shared__ int    cnt;

    const int r = blockIdx.x, tid = threadIdx.x;
    const int lane = tid & 63, w = tid >> 6;

    xr[tid]       = x[(size_t)r * Dd + tid]       - bdec[tid];
    xr[tid + 256] = x[(size_t)r * Dd + tid + 256] - bdec[tid + 256];
    xr[tid + 512] = x[(size_t)r * Dd + tid + 512] - bdec[tid + 512];
    if (tid == 0) cnt = ccount[r];
    if (tid < NCAND) cis[tid] = ci[(size_t)r * NCAND + tid];
    if (tid < Kk) { ovals[(size_t)r * Kk + tid] = 0.0f; oidx[(size_t)r * Kk + tid] = 0; }
    __syncthreads();

    for (int c = w; c < NCAND; c += 4) {
        double e = -1.0e300;
        if (c < cnt) {
            const int f = cis[c];
            const float* wrow = Wenc + (size_t)f * Dd;
            double a = 0.0;
            #pragma unroll
            for (int j = 0; j < Dd / 64; ++j)
                a = fma((double)wrow[j * 64 + lane], (double)xr[j * 64 + lane], a);
            #pragma unroll
            for (int off = 32; off > 0; off >>= 1)
                a += __shfl_xor(a, off);
            e = a + (double)benc[f];
        }
        if (lane == 0) es[c] = e;
    }
    __syncthreads();

    if (tid < NCAND) {
        const double e = es[tid];
        int rk = 0;
        for (int j = 0; j < NCAND; ++j) {
            const double ej = es[j];
            rk += (ej > e) || (ej == e && j < tid);
        }
        if (tid < cnt && rk < Kk) {
            ovals[(size_t)r * Kk + rk] = (float)e;
            oidx [(size_t)r * Kk + rk] = cis[tid];
        }
    }
}

// ---------------- W_dec transpose: [D][F] fp32 -> [F][D] bf16 ----------------
__global__ __launch_bounds__(256) void sae_transpose(
    const float* __restrict__ Wd, unsigned short* __restrict__ WdT)
{
    __shared__ float tile[32][33];
    const int f0 = blockIdx.x * 32;
    const int d0 = blockIdx.y * 32;
    const int tx = threadIdx.x, ty = threadIdx.y;
    #pragma unroll
    for (int k = 0; k < 4; ++k)
        tile[ty + 8 * k][tx] = Wd[(size_t)(d0 + ty + 8 * k) * Ff + f0 + tx];
    __syncthreads();
    #pragma unroll
    for (int k = 0; k < 4; ++k)
        WdT[(size_t)(f0 + ty + 8 * k) * Dd + d0 + tx] = f2bf(tile[tx][ty + 8 * k]);
}

// ---------------- sparse decode (bf16 WdT, LLC-resident) ----------------
// 192 threads: thread t covers d in [4t, 4t+4), reads uint2 (4 bf16) per k.
__global__ __launch_bounds__(192) void sae_decode(
    const unsigned short* __restrict__ WdT, const float* __restrict__ vals,
    const int* __restrict__ idx, const float* __restrict__ bdec,
    float* __restrict__ out)
{
    __shared__ float sv[Kk];
    __shared__ int   si[Kk];
    const int b = blockIdx.x, tid = threadIdx.x;
    if (tid < Kk) { sv[tid] = vals[(size_t)b * Kk + tid]; si[tid] = idx[(size_t)b * Kk + tid]; }
    __syncthreads();
    const int d0 = tid * 4;
    float a0 = bdec[d0], a1 = bdec[d0 + 1], a2 = bdec[d0 + 2], a3 = bdec[d0 + 3];
    for (int k = 0; k < Kk; ++k) {
        const float v = sv[k];
        const uint2 p = *(const uint2*)(WdT + (size_t)si[k] * Dd + d0);
        a0 = fmaf(v, f_lo(p.x), a0);
        a1 = fmaf(v, f_hi(p.x), a1);
        a2 = fmaf(v, f_lo(p.y), a2);
        a3 = fmaf(v, f_hi(p.y), a3);
    }
    float4 o4 = make_float4(a0, a1, a2, a3);
    *(float4*)(out + (size_t)b * Dd + d0) = o4;
}

extern "C" void kernel_launch(void* const* d_in, const int* in_sizes, int n_in,
                              void* d_out, int out_size, void* d_ws, size_t ws_size,
                              hipStream_t stream) {
    const float* x    = (const float*)d_in[0];
    const float* Wenc = (const float*)d_in[1];
    const float* benc = (const float*)d_in[2];
    const float* Wdec = (const float*)d_in[3];
    const float* bdec = (const float*)d_in[4];
    float* out = (float*)d_out;

    char* ws = (char*)d_ws;
    size_t o = 0;
    unsigned short* pre  = (unsigned short*)(ws + o); o += (size_t)Bb * Ff * 2;     // 134.2 MB
    unsigned short* Xb   = (unsigned short*)(ws + o); o += (size_t)Bb * Dd * 2;     //   6.3 MB
    unsigned short* Wb   = (unsigned short*)(ws + o); o += (size_t)Ff * Dd * 2;     //  25.2 MB
    unsigned short* WdT  = (unsigned short*)(ws + o); o += (size_t)Ff * Dd * 2;     //  25.2 MB
    int*            cib  = (int*)(ws + o);            o += (size_t)Bb * NCAND * 4;  //   2.1 MB
    int*            ccnt = (int*)(ws + o);            o += (size_t)Bb * 4;          //  16 KB
    float*          vals = (float*)(ws + o);          o += (size_t)Bb * Kk * 4;     //   1.0 MB
    int*            idxb = (int*)(ws + o);                                          //   1.0 MB

    conv_x<<<(Bb * Dd) / 256, 256, 0, stream>>>(x, bdec, Xb);
    conv_w<<<(Ff * Dd) / 256, 256, 0, stream>>>(Wenc, Wb);
    sae_gemm<<<(Bb / 256) * (Ff / 256), 512, 0, stream>>>(Xb, Wb, benc, pre);
    sae_select<<<Bb / 2, 256, 0, stream>>>(pre, cib, ccnt);
    sae_rescore<<<Bb, 256, 0, stream>>>(x, Wenc, benc, bdec, cib, ccnt, vals, idxb);
    sae_transpose<<<dim3(Ff / 32, Dd / 32), dim3(32, 8), 0, stream>>>(Wdec, WdT);
    sae_decode<<<Bb, 192, 0, stream>>>(WdT, vals, idxb, bdec, out);
}